// Round 17
// baseline (1565.988 us; speedup 1.0000x reference)
//
#include <hip/hip_runtime.h>

constexpr int B_ = 128, S_ = 25, NF_ = 196, ENC_ = 512, ATT_ = 512;
constexpr int H_ = 512, E_ = 256, V_ = 10000, G4_ = 2048;
constexpr int VPAD_ = 10112;  // 79*128

typedef __attribute__((ext_vector_type(8))) __bf16 bf16x8;
typedef __attribute__((ext_vector_type(4))) __bf16 bf16x4;
typedef __attribute__((ext_vector_type(4))) float f32x4;

__device__ __forceinline__ float bflo(unsigned u) {
    return __builtin_bit_cast(float, u << 16);
}
__device__ __forceinline__ float bfhi(unsigned u) {
    return __builtin_bit_cast(float, u & 0xffff0000u);
}
__device__ __forceinline__ float fast_tanhf(float x) {
    float e = __expf(2.f * x);
    return 1.f - 2.f * __fdividef(1.f, e + 1.f);
}
__device__ __forceinline__ float fast_sigf(float x) {
    return __fdividef(1.f, 1.f + __expf(-x));
}

// gate-interleaved permutation: col n -> weight row pi(n)
__device__ __forceinline__ int gperm(int n) {
    int j = (n & 15) + ((n >> 6) << 4);
    int g = (n >> 4) & 3;
    return g * 512 + j;
}

// async global->LDS, 16B/lane (rule #21: linear dest, swizzled global src)
__device__ __forceinline__ void gload16(const __bf16* src, __bf16* dst) {
    __builtin_amdgcn_global_load_lds(
        (const __attribute__((address_space(1))) unsigned*)src,
        (__attribute__((address_space(3))) unsigned*)dst, 16, 0, 0);
}

// ---------------- fused setup kernel (R13-proven, + flag zeroing block) ----------------
__global__ __launch_bounds__(256) void k_setup(
    const float* __restrict__ enc, __bf16* __restrict__ enc_bf,
    const float* __restrict__ Uw, __bf16* __restrict__ Uw_bf,
    const float* __restrict__ Ww, unsigned* __restrict__ W2,
    const float* __restrict__ W_ih, __bf16* __restrict__ WihE_r,
    const float* __restrict__ W_hh, __bf16* __restrict__ Wcat,
    const float* __restrict__ b_ih, const float* __restrict__ b_hh,
    float* __restrict__ bsum_r,
    const int* __restrict__ dec, const float* __restrict__ emb,
    const float* __restrict__ pose, __bf16* __restrict__ embeds_bf,
    const float* __restrict__ fcw, __bf16* __restrict__ fcw_bf,
    int* __restrict__ flag) {
    __shared__ float Ts[32][65];
    int bid = blockIdx.x, t = threadIdx.x;

    if (bid < 12544) {                       // enc cvt
        int i = bid * 256 + t;
        if (i < 3211264) {
            float4 v = *(const float4*)&enc[(size_t)i * 4];
            bf16x4 o;
            o[0] = (__bf16)v.x; o[1] = (__bf16)v.y; o[2] = (__bf16)v.z; o[3] = (__bf16)v.w;
            *(bf16x4*)&enc_bf[(size_t)i * 4] = o;
        }
    } else if (bid < 12800) {                // Uw cvt
        int i = (bid - 12544) * 256 + t;
        float4 v = *(const float4*)&Uw[(size_t)i * 4];
        bf16x4 o;
        o[0] = (__bf16)v.x; o[1] = (__bf16)v.y; o[2] = (__bf16)v.z; o[3] = (__bf16)v.w;
        *(bf16x4*)&Uw_bf[(size_t)i * 4] = o;
    } else if (bid < 12928) {                // pack_ww
        int l = bid - 12800;
        int k0 = (l & 15) * 32, j0 = (l >> 4) * 64;
        int c = t & 31, rr = t >> 5;
#pragma unroll
        for (int i = 0; i < 8; ++i) {
            int j = j0 + rr + i * 8;
            Ts[c][rr + i * 8] = Ww[(size_t)j * 512 + k0 + c];
        }
        __syncthreads();
#pragma unroll
        for (int i = 0; i < 4; ++i) {
            int kr = (t >> 5) + i * 8;
            int jc = t & 31;
            __bf16 b0 = (__bf16)Ts[kr][2 * jc], b1 = (__bf16)Ts[kr][2 * jc + 1];
            unsigned u = (unsigned)__builtin_bit_cast(unsigned short, b0)
                       | ((unsigned)__builtin_bit_cast(unsigned short, b1) << 16);
            W2[(size_t)(k0 + kr) * 256 + (j0 >> 1) + jc] = u;
        }
    } else if (bid < 14976) {                // cvt_wih_r
        int n = bid - 12928;
        int row = gperm(n);
        WihE_r[(size_t)n * 256 + t] = (__bf16)W_ih[(size_t)row * 768 + t];
    } else if (bid < 17024) {                // pack_wcat
        int n = bid - 14976;
        int row = gperm(n);
#pragma unroll
        for (int i = 0; i < 4; ++i) {
            int k = t + i * 256;
            float v = (k < 512) ? W_ih[(size_t)row * 768 + 256 + k]
                                : W_hh[(size_t)row * 512 + (k - 512)];
            Wcat[(size_t)n * 1024 + k] = (__bf16)v;
        }
    } else if (bid < 17032) {                // pack_biasr
        int n = (bid - 17024) * 256 + t;
        int row = gperm(n);
        bsum_r[n] = b_ih[row] + b_hh[row];
    } else if (bid < 20232) {                // embed
        int bx = bid - 17032;
        int s = bx >> 7, b = bx & 127;
        int tok = dec[b * S_ + s];
        embeds_bf[(size_t)bx * E_ + t] = (__bf16)(emb[tok * E_ + t] + pose[s * E_ + t]);
    } else if (bid < 25288) {                // cvt_fcw (padded)
        int i = (bid - 20232) * 256 + t;
        if (i < VPAD_ * 512 / 4) {
            int e = i * 4;
            int row = e >> 9;
            bf16x4 o;
            if (row < V_) {
                float4 v = *(const float4*)&fcw[(size_t)row * 512 + (e & 511)];
                o[0] = (__bf16)v.x; o[1] = (__bf16)v.y; o[2] = (__bf16)v.z; o[3] = (__bf16)v.w;
            } else {
                o[0] = o[1] = o[2] = o[3] = (__bf16)0.f;
            }
            *(bf16x4*)&fcw_bf[(size_t)e] = o;
        }
    } else {                                 // zero step flags
        if (t < 128) flag[t] = 0;
    }
}

// mean_enc -> h0, c0 (R13-proven)
__global__ __launch_bounds__(1024) void k_init2(const float* __restrict__ enc,
                                                const float* __restrict__ ihw, const float* __restrict__ ihb,
                                                const float* __restrict__ icw, const float* __restrict__ icb,
                                                __bf16* __restrict__ Abuf0, float* __restrict__ cbuf) {
    __shared__ float pm[1024];
    __shared__ __align__(16) float mean[512];
    int b = blockIdx.x, t = threadIdx.x;
    int d = t & 511, q = t >> 9;
    const float* ep = enc + ((size_t)b * 196 + q * 98) * 512 + d;
    float sum = 0.f;
#pragma unroll 7
    for (int n = 0; n < 98; ++n) sum += ep[(size_t)n * 512];
    pm[t] = sum;
    __syncthreads();
    if (t < 512) mean[t] = (pm[t] + pm[t + 512]) * (1.f / 196.f);
    __syncthreads();
    int w = t >> 6, ln = t & 63;
    float4 m4a = *(const float4*)&mean[ln * 8];
    float4 m4b = *(const float4*)&mean[ln * 8 + 4];
#pragma unroll 4
    for (int i = 0; i < 32; ++i) {
        int j = i * 16 + w;
        const float4* wh = (const float4*)&ihw[(size_t)j * 512 + ln * 8];
        const float4* wc = (const float4*)&icw[(size_t)j * 512 + ln * 8];
        float4 ha = wh[0], hb = wh[1], ca = wc[0], cb = wc[1];
        float ah = m4a.x * ha.x + m4a.y * ha.y + m4a.z * ha.z + m4a.w * ha.w
                 + m4b.x * hb.x + m4b.y * hb.y + m4b.z * hb.z + m4b.w * hb.w;
        float ac = m4a.x * ca.x + m4a.y * ca.y + m4a.z * ca.z + m4a.w * ca.w
                 + m4b.x * cb.x + m4b.y * cb.y + m4b.z * cb.z + m4b.w * cb.w;
#pragma unroll
        for (int off = 32; off; off >>= 1) {
            ah += __shfl_xor(ah, off);
            ac += __shfl_xor(ac, off);
        }
        if (ln == 0) {
            Abuf0[(size_t)b * 1024 + 512 + j] = (__bf16)(ah + ihb[j]);
            cbuf[b * 512 + j] = ac + icb[j];
        }
    }
}

// ---------------- fused setup GEMMs, global_load_lds staging (R15) ----------------
__global__ __launch_bounds__(256) void k_gemms(
    const __bf16* __restrict__ Aa, const __bf16* __restrict__ Ba,
    const float* __restrict__ ba, __bf16* __restrict__ Ca,
    const __bf16* __restrict__ Ab, const __bf16* __restrict__ Bb,
    const float* __restrict__ bb, __bf16* __restrict__ Cb) {
    __shared__ __align__(16) __bf16 As[128 * 64];
    __shared__ __align__(16) __bf16 Bs[128 * 64];
    int bid = blockIdx.x, tid = threadIdx.x;
    const __bf16 *A, *Bm;
    const float* bias;
    __bf16* C;
    int lda, K, ldc, m0, n0;
    if (bid < 784) {
        A = Aa; Bm = Ba; bias = ba; C = Ca; lda = 512; K = 512; ldc = 512;
        m0 = (bid % 196) * 128; n0 = (bid / 196) * 128;
    } else {
        int i = bid - 784;
        A = Ab; Bm = Bb; bias = bb; C = Cb; lda = 256; K = 256; ldc = 2048;
        m0 = (i % 25) * 128; n0 = (i / 25) * 128;
    }
    int lane = tid & 63, w = tid >> 6;
    int wm = (w & 1) * 64, wn = (w >> 1) * 64;
    f32x4 acc[4][4] = {};
    int lrow = lane >> 3;
    int kgd = lane & 7;

    for (int k0 = 0; k0 < K; k0 += 64) {
#pragma unroll
        for (int i = 0; i < 4; ++i) {
            int row = w * 32 + i * 8 + lrow;
            int kgs = kgd ^ (row & 7);
            gload16(A + (size_t)(m0 + row) * lda + k0 + kgs * 8, &As[row * 64 + kgd * 8]);
            gload16(Bm + (size_t)(n0 + row) * K + k0 + kgs * 8, &Bs[row * 64 + kgd * 8]);
        }
        __syncthreads();
        bf16x8 af[4][2], bfr[4][2];
#pragma unroll
        for (int f = 0; f < 4; ++f) {
#pragma unroll
            for (int ks = 0; ks < 2; ++ks) {
                int ra = wm + f * 16 + (lane & 15);
                int rb = wn + f * 16 + (lane & 15);
                int kgl = ks * 4 + (lane >> 4);
                af[f][ks]  = *(const bf16x8*)&As[ra * 64 + (kgl ^ (ra & 7)) * 8];
                bfr[f][ks] = *(const bf16x8*)&Bs[rb * 64 + (kgl ^ (rb & 7)) * 8];
            }
        }
#pragma unroll
        for (int fm = 0; fm < 4; ++fm)
#pragma unroll
            for (int fn = 0; fn < 4; ++fn)
#pragma unroll
                for (int ks = 0; ks < 2; ++ks)
                    acc[fm][fn] = __builtin_amdgcn_mfma_f32_16x16x32_bf16(
                        af[fm][ks], bfr[fn][ks], acc[fm][fn], 0, 0, 0);
        __syncthreads();
    }
    int cm = (lane >> 4) * 4, cn = lane & 15;
#pragma unroll
    for (int fm = 0; fm < 4; ++fm)
#pragma unroll
        for (int fn = 0; fn < 4; ++fn)
#pragma unroll
            for (int r = 0; r < 4; ++r) {
                int gm = m0 + wm + fm * 16 + cm + r;
                int gn = n0 + wn + fn * 16 + cn;
                C[(size_t)gm * ldc + gn] = (__bf16)(acc[fm][fn][r] + bias[gn]);
            }
}

// ---------------- fcn GEMM (R15) ----------------
__global__ __launch_bounds__(256) void k_fcn(
    const __bf16* __restrict__ A, const __bf16* __restrict__ Bm,
    const float* __restrict__ bias1, float* __restrict__ Cout) {
    __shared__ __align__(16) __bf16 As[128 * 64];
    __shared__ __align__(16) __bf16 Bs[128 * 64];
    int tid = threadIdx.x;
    int lane = tid & 63, w = tid >> 6;
    int nwg = gridDim.x * gridDim.y;
    int bid = blockIdx.y * gridDim.x + blockIdx.x;
    int q = nwg >> 3, r0 = nwg & 7;
    int xcd = bid & 7, lid = bid >> 3;
    int wgid = (xcd < r0) ? xcd * (q + 1) + lid : r0 * (q + 1) + (xcd - r0) * q + lid;
    int m0 = (wgid % gridDim.x) * 128;
    int n0 = (wgid / gridDim.x) * 128;

    int wm = (w & 1) * 64, wn = (w >> 1) * 64;
    f32x4 acc[4][4] = {};
    int lrow = lane >> 3;
    int kgd = lane & 7;

    for (int k0 = 0; k0 < 512; k0 += 64) {
#pragma unroll
        for (int i = 0; i < 4; ++i) {
            int row = w * 32 + i * 8 + lrow;
            int kgs = kgd ^ (row & 7);
            gload16(A + (size_t)(m0 + row) * 512 + k0 + kgs * 8, &As[row * 64 + kgd * 8]);
            gload16(Bm + (size_t)(n0 + row) * 512 + k0 + kgs * 8, &Bs[row * 64 + kgd * 8]);
        }
        __syncthreads();
        bf16x8 af[4][2], bfr[4][2];
#pragma unroll
        for (int f = 0; f < 4; ++f) {
#pragma unroll
            for (int ks = 0; ks < 2; ++ks) {
                int ra = wm + f * 16 + (lane & 15);
                int rb = wn + f * 16 + (lane & 15);
                int kgl = ks * 4 + (lane >> 4);
                af[f][ks]  = *(const bf16x8*)&As[ra * 64 + (kgl ^ (ra & 7)) * 8];
                bfr[f][ks] = *(const bf16x8*)&Bs[rb * 64 + (kgl ^ (rb & 7)) * 8];
            }
        }
#pragma unroll
        for (int fm = 0; fm < 4; ++fm)
#pragma unroll
            for (int fn = 0; fn < 4; ++fn)
#pragma unroll
                for (int ks = 0; ks < 2; ++ks)
                    acc[fm][fn] = __builtin_amdgcn_mfma_f32_16x16x32_bf16(
                        af[fm][ks], bfr[fn][ks], acc[fm][fn], 0, 0, 0);
        __syncthreads();
    }
    int cm = (lane >> 4) * 4, cn = lane & 15;
#pragma unroll
    for (int fm = 0; fm < 4; ++fm) {
#pragma unroll
        for (int fn = 0; fn < 4; ++fn) {
#pragma unroll
            for (int r = 0; r < 4; ++r) {
                int gm = m0 + wm + fm * 16 + cm + r;
                int gn = n0 + wn + fn * 16 + cn;
                if (gn < V_) {
                    int orow = (gm & 127) * S_ + (gm >> 7);
                    Cout[(size_t)orow * V_ + gn] = acc[fm][fn][r] + bias1[gn];
                }
            }
        }
    }
}

// ---------------- fused per-step kernel: 384 blocks ----------------
// blocks 0..127  (1024 thr used): R15 attn body (b = bid) -> ctx into Abuf, RELEASE flag[b]=s+1
// blocks 128..383 (256 thr used): RELAXED-poll 16 flags (1/lane) + one acquire fence,
//                                 then R15 gates body (m0=(gbk&7)*16, n0=(gbk>>3)*64)
__global__ __launch_bounds__(1024) void k_step(
    const __bf16* __restrict__ u_hs, const unsigned* __restrict__ enc2,
    const unsigned* __restrict__ W2, const float* __restrict__ Wb,
    const float* __restrict__ Aw, const __bf16* __restrict__ Wcat,
    const __bf16* __restrict__ gatespre, float* __restrict__ cbuf,
    __bf16* __restrict__ Abuf, __bf16* __restrict__ AbufN,
    __bf16* __restrict__ Hall_bf, float* __restrict__ alphas,
    int* __restrict__ flag, int s) {
    // attn-role LDS
    __shared__ __align__(16) float hs[512];
    __shared__ float wah[512];
    __shared__ float pc[2048];
    __shared__ float sc[200];
    // gates-role LDS
    __shared__ __align__(16) __bf16 Asg[2][16 * 64];
    __shared__ __align__(16) __bf16 Bsg[2][64 * 64];
    __shared__ float Red[1024];
    __shared__ float Gs[16][68];

    int bid = blockIdx.x, t = threadIdx.x;

    if (bid < 128) {
        // ================= ATTN ROLE (R15 k_attn2 verbatim, b = bid) =================
        int b = bid;
        int ln = t & 63, w = t >> 6;
        if (t < 256) {
            unsigned u = ((const unsigned*)Abuf)[b * 512 + 256 + t];
            hs[2 * t] = bflo(u); hs[2 * t + 1] = bfhi(u);
        }
        __syncthreads();
        {
            int jp = t & 255, kq = t >> 8;
            float a0 = 0.f, a1 = 0.f;
            const unsigned* wp = W2 + (size_t)(kq * 128) * 256 + jp;
            const float4* h4 = (const float4*)(hs + kq * 128);
#pragma unroll 4
            for (int k4 = 0; k4 < 32; ++k4) {
                float4 hk = h4[k4];
                unsigned w0 = wp[(k4 * 4 + 0) * 256];
                unsigned w1 = wp[(k4 * 4 + 1) * 256];
                unsigned w2 = wp[(k4 * 4 + 2) * 256];
                unsigned w3 = wp[(k4 * 4 + 3) * 256];
                a0 += hk.x * bflo(w0); a1 += hk.x * bfhi(w0);
                a0 += hk.y * bflo(w1); a1 += hk.y * bfhi(w1);
                a0 += hk.z * bflo(w2); a1 += hk.z * bfhi(w2);
                a0 += hk.w * bflo(w3); a1 += hk.w * bfhi(w3);
            }
            pc[kq * 512 + 2 * jp] = a0;
            pc[kq * 512 + 2 * jp + 1] = a1;
        }
        __syncthreads();
        if (t < 512)
            wah[t] = pc[t] + pc[512 + t] + pc[1024 + t] + pc[1536 + t] + Wb[t];
        __syncthreads();
        {
            float av[8], wv[8];
#pragma unroll
            for (int i = 0; i < 8; ++i) { av[i] = Aw[ln * 8 + i]; wv[i] = wah[ln * 8 + i]; }
            for (int n = w; n < NF_; n += 16) {
                bf16x8 u8 = *(const bf16x8*)(u_hs + ((size_t)(b * NF_ + n)) * 512 + ln * 8);
                float acc = 0.f;
#pragma unroll
                for (int i = 0; i < 8; ++i)
                    acc += fast_tanhf((float)u8[i] + wv[i]) * av[i];
#pragma unroll
                for (int off = 32; off; off >>= 1) acc += __shfl_xor(acc, off);
                if (ln == 0) sc[n] = __expf(acc);
            }
        }
        __syncthreads();
        // wave-redundant normalizer: 196 = 3*64 + 4 (R11-fixed)
        float sum = sc[ln] + sc[ln + 64] + sc[ln + 128];
        if (ln < 4) sum += sc[ln + 192];
#pragma unroll
        for (int off = 32; off; off >>= 1) sum += __shfl_xor(sum, off);
        float inv = __fdividef(1.f, sum);
        if (t < NF_) alphas[((size_t)b * S_ + s) * NF_ + t] = sc[t] * inv;
        {
            int p2 = t & 255, q2 = t >> 8;
            float c0 = 0.f, c1 = 0.f;
            for (int i = q2; i < NF_; i += 4) {
                unsigned u = enc2[((size_t)(b * NF_ + i)) * 256 + p2];
                float a = sc[i];
                c0 += a * bflo(u); c1 += a * bfhi(u);
            }
            pc[q2 * 512 + 2 * p2] = c0;
            pc[q2 * 512 + 2 * p2 + 1] = c1;
        }
        __syncthreads();
        if (t < 512)
            Abuf[(size_t)b * 1024 + t] =
                (__bf16)((pc[t] + pc[512 + t] + pc[1024 + t] + pc[1536 + t]) * inv);
        __syncthreads();   // drains all threads' vmcnt -> ctx stores in L2
        if (t == 0) {
            __threadfence();   // agent release ordering
            __hip_atomic_store(&flag[b], s + 1, __ATOMIC_RELEASE, __HIP_MEMORY_SCOPE_AGENT);
        }
    } else {
        // ================= GATES ROLE (R15 k_gates verbatim) =================
        if (t >= 256) return;   // exited waves don't count toward s_barrier
        int gbk = bid - 128;
        int m0 = (gbk & 7) * 16, n0 = (gbk >> 3) * 64;
        // RELAXED poll (no per-iteration L1 invalidation), long sleep, one acquire after
        if (t < 64) {
            for (;;) {
                int v = (t < 16)
                    ? __hip_atomic_load(&flag[m0 + t], __ATOMIC_RELAXED, __HIP_MEMORY_SCOPE_AGENT)
                    : 0x7fffffff;
                if (__all(v >= s + 1)) break;
                __builtin_amdgcn_s_sleep(32);
            }
            __threadfence();   // single acquire-side fence (L1 invalidate once)
        }
        __syncthreads();

        int lane = t & 63, w = t >> 6;
        int kh = w >> 1, nh = w & 1;
        f32x4 acc[2] = {};
        int ah = t >> 7;
        int arow = (t & 127) >> 3;
        int ake = (t & 7) * 8;
        int akg = t & 7;
        int srow = t >> 3;
        int ke = (t & 7) * 8;
        int kgw = t & 7;

        for (int k0 = 0; k0 < 512; k0 += 64) {
            {
                int kb = ah * 512 + k0;
                bf16x8 av = *(const bf16x8*)(Abuf + (size_t)(m0 + arow) * 1024 + kb + ake);
                *(bf16x8*)&Asg[ah][arow * 64 + (akg ^ (arow & 7)) * 8] = av;
            }
#pragma unroll
            for (int h = 0; h < 2; ++h) {
                int kb = h * 512 + k0;
#pragma unroll
                for (int it = 0; it < 2; ++it) {
                    int row = it * 32 + srow;
                    bf16x8 bv = *(const bf16x8*)(Wcat + (size_t)(n0 + row) * 1024 + kb + ke);
                    *(bf16x8*)&Bsg[h][row * 64 + (kgw ^ (row & 7)) * 8] = bv;
                }
            }
            __syncthreads();
            bf16x8 af[2], bfr[2][2];
#pragma unroll
            for (int ks = 0; ks < 2; ++ks) {
                int ra = lane & 15;
                int kgl = ks * 4 + (lane >> 4);
                af[ks] = *(const bf16x8*)&Asg[kh][ra * 64 + ((kgl ^ (ra & 7))) * 8];
#pragma unroll
                for (int fn = 0; fn < 2; ++fn) {
                    int rb = nh * 32 + fn * 16 + (lane & 15);
                    bfr[fn][ks] = *(const bf16x8*)&Bsg[kh][rb * 64 + ((kgl ^ (rb & 7))) * 8];
                }
            }
#pragma unroll
            for (int fn = 0; fn < 2; ++fn)
#pragma unroll
                for (int ks = 0; ks < 2; ++ks)
                    acc[fn] = __builtin_amdgcn_mfma_f32_16x16x32_bf16(
                        af[ks], bfr[fn][ks], acc[fn], 0, 0, 0);
            __syncthreads();
        }
        int base = (nh * 64 + lane) * 8;
        if (kh == 1) {
#pragma unroll
            for (int fn = 0; fn < 2; ++fn)
#pragma unroll
                for (int r = 0; r < 4; ++r) Red[base + fn * 4 + r] = acc[fn][r];
        }
        __syncthreads();
        if (kh == 0) {
            int cm = (lane >> 4) * 4, cn = lane & 15;
#pragma unroll
            for (int fn = 0; fn < 2; ++fn)
#pragma unroll
                for (int r = 0; r < 4; ++r)
                    Gs[cm + r][nh * 32 + fn * 16 + cn] = acc[fn][r] + Red[base + fn * 4 + r];
        }
        __syncthreads();
        {
            int row = t >> 4, jlo = t & 15;
            int b = m0 + row;
            int j = (n0 >> 6) * 16 + jlo;
            const __bf16* gp = gatespre + ((size_t)(s * B_ + b)) * G4_ + n0 + jlo;
            float qi = Gs[row][jlo]      + (float)gp[0];
            float qf = Gs[row][16 + jlo] + (float)gp[16];
            float qg = Gs[row][32 + jlo] + (float)gp[32];
            float qo = Gs[row][48 + jlo] + (float)gp[48];
            float ig = fast_sigf(qi), fg = fast_sigf(qf);
            float gg = fast_tanhf(qg), og = fast_sigf(qo);
            int ci = b * 512 + j;
            float cnew = fg * cbuf[ci] + ig * gg;
            float hn = og * fast_tanhf(cnew);
            cbuf[ci] = cnew;
            __bf16 hb = (__bf16)hn;
            AbufN[(size_t)b * 1024 + 512 + j] = hb;
            Hall_bf[(size_t)(s + 1) * 65536 + ci] = hb;
        }
    }
}

extern "C" void kernel_launch(void* const* d_in, const int* in_sizes, int n_in,
                              void* d_out, int out_size, void* d_ws, size_t ws_size,
                              hipStream_t stream) {
    const int*   dec  = (const int*)d_in[0];
    const float* enc  = (const float*)d_in[1];
    const float* emb  = (const float*)d_in[2];
    const float* pose = (const float*)d_in[3];
    const float* Uw   = (const float*)d_in[4];
    const float* Ub   = (const float*)d_in[5];
    const float* Ww   = (const float*)d_in[6];
    const float* Wb   = (const float*)d_in[7];
    const float* Aw   = (const float*)d_in[8];
    // d_in[9] = Ab: cancels in softmax
    const float* ihw  = (const float*)d_in[10];
    const float* ihb  = (const float*)d_in[11];
    const float* icw  = (const float*)d_in[12];
    const float* icb  = (const float*)d_in[13];
    const float* W_ih = (const float*)d_in[14];
    const float* W_hh = (const float*)d_in[15];
    const float* b_ih = (const float*)d_in[16];
    const float* b_hh = (const float*)d_in[17];
    const float* fcw  = (const float*)d_in[18];
    const float* fcb  = (const float*)d_in[19];
    float* out = (float*)d_out;
    char*  wsb = (char*)d_ws;

    // ---- workspace layout (bytes), ~87 MB ----
    size_t o = 0;
    __bf16*   enc_bf   = (__bf16*)(wsb + o); o += (size_t)25088 * 512 * 2;
    __bf16*   u_hs_bf  = (__bf16*)(wsb + o); o += (size_t)25088 * 512 * 2;
    __bf16*   gpre_bf  = (__bf16*)(wsb + o); o += (size_t)3200 * 2048 * 2;
    __bf16*   Hall_bf  = (__bf16*)(wsb + o); o += (size_t)26 * 65536 * 2;
    float*    cbuf     = (float*)(wsb + o);  o += (size_t)65536 * 4;
    __bf16*   Abuf     = (__bf16*)(wsb + o); o += (size_t)2 * 128 * 1024 * 2;
    __bf16*   Uw_bf    = (__bf16*)(wsb + o); o += (size_t)262144 * 2;
    unsigned* W2       = (unsigned*)(wsb + o); o += (size_t)512 * 256 * 4;
    __bf16*   WihE_r   = (__bf16*)(wsb + o); o += (size_t)2048 * 256 * 2;
    __bf16*   embeds_bf= (__bf16*)(wsb + o); o += (size_t)3200 * 256 * 2;
    __bf16*   Wcat     = (__bf16*)(wsb + o); o += (size_t)2048 * 1024 * 2;
    float*    bsum_r   = (float*)(wsb + o);  o += (size_t)2048 * 4;
    __bf16*   fcw_bf   = (__bf16*)(wsb + o); o += (size_t)VPAD_ * 512 * 2;
    int*      flags    = (int*)(wsb + o);    o += 128 * 4;

    // ---- setup: one fused launch + init + one fused GEMM launch ----
    k_setup<<<25289, 256, 0, stream>>>(enc, enc_bf, Uw, Uw_bf, Ww, W2,
                                       W_ih, WihE_r, W_hh, Wcat,
                                       b_ih, b_hh, bsum_r,
                                       dec, emb, pose, embeds_bf, fcw, fcw_bf, flags);
    k_init2<<<B_, 1024, 0, stream>>>(enc, ihw, ihb, icw, icb, Abuf, cbuf);
    k_gemms<<<1184, 256, 0, stream>>>(enc_bf, Uw_bf, Ub, u_hs_bf,
                                      embeds_bf, WihE_r, bsum_r, gpre_bf);

    // ---- 25 steps x 1 fused kernel (relaxed-poll producer/consumer) ----
    for (int s = 0; s < S_; ++s) {
        __bf16* Ap = Abuf + (size_t)(s & 1) * 131072;
        __bf16* An = Abuf + (size_t)((s + 1) & 1) * 131072;
        k_step<<<384, 1024, 0, stream>>>(u_hs_bf, (const unsigned*)enc_bf, W2, Wb, Aw,
                                         Wcat, gpre_bf, cbuf, Ap, An, Hall_bf,
                                         out + 32000000, flags, s);
    }

    // outs = Hall_bf[1..25] @ fcn_w^T + fcn_b -> f32 [B,S,V]  (XCD-swizzled, direct stores)
    k_fcn<<<dim3(25, 79), 256, 0, stream>>>(Hall_bf + 65536, fcw_bf, fcb, out);
}

// Round 18
// 1335.053 us; speedup vs baseline: 1.1730x; 1.1730x over previous
//
#include <hip/hip_runtime.h>

constexpr int B_ = 128, S_ = 25, NF_ = 196, ENC_ = 512, ATT_ = 512;
constexpr int H_ = 512, E_ = 256, V_ = 10000, G4_ = 2048;
constexpr int VPAD_ = 10112;  // 79*128

typedef __attribute__((ext_vector_type(8))) __bf16 bf16x8;
typedef __attribute__((ext_vector_type(4))) __bf16 bf16x4;
typedef __attribute__((ext_vector_type(4))) float f32x4;

__device__ __forceinline__ float bflo(unsigned u) {
    return __builtin_bit_cast(float, u << 16);
}
__device__ __forceinline__ float bfhi(unsigned u) {
    return __builtin_bit_cast(float, u & 0xffff0000u);
}
// clamp-free: e=inf/0 degrade gracefully to +-1 (no NaN possible for finite x)
__device__ __forceinline__ float fast_tanhf(float x) {
    float e = __expf(2.f * x);
    return 1.f - 2.f * __fdividef(1.f, e + 1.f);
}
__device__ __forceinline__ float fast_sigf(float x) {
    return __fdividef(1.f, 1.f + __expf(-x));
}

// gate-interleaved permutation: col n -> weight row pi(n)
__device__ __forceinline__ int gperm(int n) {
    int j = (n & 15) + ((n >> 6) << 4);
    int g = (n >> 4) & 3;
    return g * 512 + j;
}

// async global->LDS, 16B/lane. dest linear in lane order (rule #21); swizzle on global src.
__device__ __forceinline__ void gload16(const __bf16* src, __bf16* dst) {
    __builtin_amdgcn_global_load_lds(
        (const __attribute__((address_space(1))) unsigned*)src,
        (__attribute__((address_space(3))) unsigned*)dst, 16, 0, 0);
}

// ---------------- fused setup kernel (R13-proven) ----------------
__global__ __launch_bounds__(256) void k_setup(
    const float* __restrict__ enc, __bf16* __restrict__ enc_bf,
    const float* __restrict__ Uw, __bf16* __restrict__ Uw_bf,
    const float* __restrict__ Ww, unsigned* __restrict__ W2,
    const float* __restrict__ W_ih, __bf16* __restrict__ WihE_r,
    const float* __restrict__ W_hh, __bf16* __restrict__ Wcat,
    const float* __restrict__ b_ih, const float* __restrict__ b_hh,
    float* __restrict__ bsum_r,
    const int* __restrict__ dec, const float* __restrict__ emb,
    const float* __restrict__ pose, __bf16* __restrict__ embeds_bf,
    const float* __restrict__ fcw, __bf16* __restrict__ fcw_bf) {
    __shared__ float Ts[32][65];
    int bid = blockIdx.x, t = threadIdx.x;

    if (bid < 12544) {                       // enc cvt
        int i = bid * 256 + t;
        if (i < 3211264) {
            float4 v = *(const float4*)&enc[(size_t)i * 4];
            bf16x4 o;
            o[0] = (__bf16)v.x; o[1] = (__bf16)v.y; o[2] = (__bf16)v.z; o[3] = (__bf16)v.w;
            *(bf16x4*)&enc_bf[(size_t)i * 4] = o;
        }
    } else if (bid < 12800) {                // Uw cvt
        int i = (bid - 12544) * 256 + t;
        float4 v = *(const float4*)&Uw[(size_t)i * 4];
        bf16x4 o;
        o[0] = (__bf16)v.x; o[1] = (__bf16)v.y; o[2] = (__bf16)v.z; o[3] = (__bf16)v.w;
        *(bf16x4*)&Uw_bf[(size_t)i * 4] = o;
    } else if (bid < 12928) {                // pack_ww
        int l = bid - 12800;
        int k0 = (l & 15) * 32, j0 = (l >> 4) * 64;
        int c = t & 31, rr = t >> 5;
#pragma unroll
        for (int i = 0; i < 8; ++i) {
            int j = j0 + rr + i * 8;
            Ts[c][rr + i * 8] = Ww[(size_t)j * 512 + k0 + c];
        }
        __syncthreads();
#pragma unroll
        for (int i = 0; i < 4; ++i) {
            int kr = (t >> 5) + i * 8;
            int jc = t & 31;
            __bf16 b0 = (__bf16)Ts[kr][2 * jc], b1 = (__bf16)Ts[kr][2 * jc + 1];
            unsigned u = (unsigned)__builtin_bit_cast(unsigned short, b0)
                       | ((unsigned)__builtin_bit_cast(unsigned short, b1) << 16);
            W2[(size_t)(k0 + kr) * 256 + (j0 >> 1) + jc] = u;
        }
    } else if (bid < 14976) {                // cvt_wih_r
        int n = bid - 12928;
        int row = gperm(n);
        WihE_r[(size_t)n * 256 + t] = (__bf16)W_ih[(size_t)row * 768 + t];
    } else if (bid < 17024) {                // pack_wcat
        int n = bid - 14976;
        int row = gperm(n);
#pragma unroll
        for (int i = 0; i < 4; ++i) {
            int k = t + i * 256;
            float v = (k < 512) ? W_ih[(size_t)row * 768 + 256 + k]
                                : W_hh[(size_t)row * 512 + (k - 512)];
            Wcat[(size_t)n * 1024 + k] = (__bf16)v;
        }
    } else if (bid < 17032) {                // pack_biasr
        int n = (bid - 17024) * 256 + t;
        int row = gperm(n);
        bsum_r[n] = b_ih[row] + b_hh[row];
    } else if (bid < 20232) {                // embed
        int bx = bid - 17032;
        int s = bx >> 7, b = bx & 127;
        int tok = dec[b * S_ + s];
        embeds_bf[(size_t)bx * E_ + t] = (__bf16)(emb[tok * E_ + t] + pose[s * E_ + t]);
    } else {                                 // cvt_fcw (padded)
        int i = (bid - 20232) * 256 + t;
        if (i < VPAD_ * 512 / 4) {
            int e = i * 4;
            int row = e >> 9;
            bf16x4 o;
            if (row < V_) {
                float4 v = *(const float4*)&fcw[(size_t)row * 512 + (e & 511)];
                o[0] = (__bf16)v.x; o[1] = (__bf16)v.y; o[2] = (__bf16)v.z; o[3] = (__bf16)v.w;
            } else {
                o[0] = o[1] = o[2] = o[3] = (__bf16)0.f;
            }
            *(bf16x4*)&fcw_bf[(size_t)e] = o;
        }
    }
}

// mean_enc -> h0, c0 (R13-proven)
__global__ __launch_bounds__(1024) void k_init2(const float* __restrict__ enc,
                                                const float* __restrict__ ihw, const float* __restrict__ ihb,
                                                const float* __restrict__ icw, const float* __restrict__ icb,
                                                __bf16* __restrict__ Abuf0, float* __restrict__ cbuf) {
    __shared__ float pm[1024];
    __shared__ __align__(16) float mean[512];
    int b = blockIdx.x, t = threadIdx.x;
    int d = t & 511, q = t >> 9;
    const float* ep = enc + ((size_t)b * 196 + q * 98) * 512 + d;
    float sum = 0.f;
#pragma unroll 7
    for (int n = 0; n < 98; ++n) sum += ep[(size_t)n * 512];
    pm[t] = sum;
    __syncthreads();
    if (t < 512) mean[t] = (pm[t] + pm[t + 512]) * (1.f / 196.f);
    __syncthreads();
    int w = t >> 6, ln = t & 63;
    float4 m4a = *(const float4*)&mean[ln * 8];
    float4 m4b = *(const float4*)&mean[ln * 8 + 4];
#pragma unroll 4
    for (int i = 0; i < 32; ++i) {
        int j = i * 16 + w;
        const float4* wh = (const float4*)&ihw[(size_t)j * 512 + ln * 8];
        const float4* wc = (const float4*)&icw[(size_t)j * 512 + ln * 8];
        float4 ha = wh[0], hb = wh[1], ca = wc[0], cb = wc[1];
        float ah = m4a.x * ha.x + m4a.y * ha.y + m4a.z * ha.z + m4a.w * ha.w
                 + m4b.x * hb.x + m4b.y * hb.y + m4b.z * hb.z + m4b.w * hb.w;
        float ac = m4a.x * ca.x + m4a.y * ca.y + m4a.z * ca.z + m4a.w * ca.w
                 + m4b.x * cb.x + m4b.y * cb.y + m4b.z * cb.z + m4b.w * cb.w;
#pragma unroll
        for (int off = 32; off; off >>= 1) {
            ah += __shfl_xor(ah, off);
            ac += __shfl_xor(ac, off);
        }
        if (ln == 0) {
            Abuf0[(size_t)b * 1024 + 512 + j] = (__bf16)(ah + ihb[j]);
            cbuf[b * 512 + j] = ac + icb[j];
        }
    }
}

// ---------------- fused setup GEMMs, global_load_lds staging (R15) ----------------
__global__ __launch_bounds__(256) void k_gemms(
    const __bf16* __restrict__ Aa, const __bf16* __restrict__ Ba,
    const float* __restrict__ ba, __bf16* __restrict__ Ca,
    const __bf16* __restrict__ Ab, const __bf16* __restrict__ Bb,
    const float* __restrict__ bb, __bf16* __restrict__ Cb) {
    __shared__ __align__(16) __bf16 As[128 * 64];
    __shared__ __align__(16) __bf16 Bs[128 * 64];
    int bid = blockIdx.x, tid = threadIdx.x;
    const __bf16 *A, *Bm;
    const float* bias;
    __bf16* C;
    int lda, K, ldc, m0, n0;
    if (bid < 784) {
        A = Aa; Bm = Ba; bias = ba; C = Ca; lda = 512; K = 512; ldc = 512;
        m0 = (bid % 196) * 128; n0 = (bid / 196) * 128;
    } else {
        int i = bid - 784;
        A = Ab; Bm = Bb; bias = bb; C = Cb; lda = 256; K = 256; ldc = 2048;
        m0 = (i % 25) * 128; n0 = (i / 25) * 128;
    }
    int lane = tid & 63, w = tid >> 6;
    int wm = (w & 1) * 64, wn = (w >> 1) * 64;
    f32x4 acc[4][4] = {};
    int lrow = lane >> 3;
    int kgd = lane & 7;

    for (int k0 = 0; k0 < K; k0 += 64) {
#pragma unroll
        for (int i = 0; i < 4; ++i) {
            int row = w * 32 + i * 8 + lrow;
            int kgs = kgd ^ (row & 7);
            gload16(A + (size_t)(m0 + row) * lda + k0 + kgs * 8, &As[row * 64 + kgd * 8]);
            gload16(Bm + (size_t)(n0 + row) * K + k0 + kgs * 8, &Bs[row * 64 + kgd * 8]);
        }
        __syncthreads();
        bf16x8 af[4][2], bfr[4][2];
#pragma unroll
        for (int f = 0; f < 4; ++f) {
#pragma unroll
            for (int ks = 0; ks < 2; ++ks) {
                int ra = wm + f * 16 + (lane & 15);
                int rb = wn + f * 16 + (lane & 15);
                int kgl = ks * 4 + (lane >> 4);
                af[f][ks]  = *(const bf16x8*)&As[ra * 64 + (kgl ^ (ra & 7)) * 8];
                bfr[f][ks] = *(const bf16x8*)&Bs[rb * 64 + (kgl ^ (rb & 7)) * 8];
            }
        }
#pragma unroll
        for (int fm = 0; fm < 4; ++fm)
#pragma unroll
            for (int fn = 0; fn < 4; ++fn)
#pragma unroll
                for (int ks = 0; ks < 2; ++ks)
                    acc[fm][fn] = __builtin_amdgcn_mfma_f32_16x16x32_bf16(
                        af[fm][ks], bfr[fn][ks], acc[fm][fn], 0, 0, 0);
        __syncthreads();
    }
    int cm = (lane >> 4) * 4, cn = lane & 15;
#pragma unroll
    for (int fm = 0; fm < 4; ++fm)
#pragma unroll
        for (int fn = 0; fn < 4; ++fn)
#pragma unroll
            for (int r = 0; r < 4; ++r) {
                int gm = m0 + wm + fm * 16 + cm + r;
                int gn = n0 + wn + fn * 16 + cn;
                C[(size_t)gm * ldc + gn] = (__bf16)(acc[fm][fn][r] + bias[gn]);
            }
}

// ---------------- fcn GEMM (R15) ----------------
__global__ __launch_bounds__(256) void k_fcn(
    const __bf16* __restrict__ A, const __bf16* __restrict__ Bm,
    const float* __restrict__ bias1, float* __restrict__ Cout) {
    __shared__ __align__(16) __bf16 As[128 * 64];
    __shared__ __align__(16) __bf16 Bs[128 * 64];
    int tid = threadIdx.x;
    int lane = tid & 63, w = tid >> 6;
    int nwg = gridDim.x * gridDim.y;
    int bid = blockIdx.y * gridDim.x + blockIdx.x;
    int q = nwg >> 3, r0 = nwg & 7;
    int xcd = bid & 7, lid = bid >> 3;
    int wgid = (xcd < r0) ? xcd * (q + 1) + lid : r0 * (q + 1) + (xcd - r0) * q + lid;
    int m0 = (wgid % gridDim.x) * 128;
    int n0 = (wgid / gridDim.x) * 128;

    int wm = (w & 1) * 64, wn = (w >> 1) * 64;
    f32x4 acc[4][4] = {};
    int lrow = lane >> 3;
    int kgd = lane & 7;

    for (int k0 = 0; k0 < 512; k0 += 64) {
#pragma unroll
        for (int i = 0; i < 4; ++i) {
            int row = w * 32 + i * 8 + lrow;
            int kgs = kgd ^ (row & 7);
            gload16(A + (size_t)(m0 + row) * 512 + k0 + kgs * 8, &As[row * 64 + kgd * 8]);
            gload16(Bm + (size_t)(n0 + row) * 512 + k0 + kgs * 8, &Bs[row * 64 + kgd * 8]);
        }
        __syncthreads();
        bf16x8 af[4][2], bfr[4][2];
#pragma unroll
        for (int f = 0; f < 4; ++f) {
#pragma unroll
            for (int ks = 0; ks < 2; ++ks) {
                int ra = wm + f * 16 + (lane & 15);
                int rb = wn + f * 16 + (lane & 15);
                int kgl = ks * 4 + (lane >> 4);
                af[f][ks]  = *(const bf16x8*)&As[ra * 64 + (kgl ^ (ra & 7)) * 8];
                bfr[f][ks] = *(const bf16x8*)&Bs[rb * 64 + (kgl ^ (rb & 7)) * 8];
            }
        }
#pragma unroll
        for (int fm = 0; fm < 4; ++fm)
#pragma unroll
            for (int fn = 0; fn < 4; ++fn)
#pragma unroll
                for (int ks = 0; ks < 2; ++ks)
                    acc[fm][fn] = __builtin_amdgcn_mfma_f32_16x16x32_bf16(
                        af[fm][ks], bfr[fn][ks], acc[fm][fn], 0, 0, 0);
        __syncthreads();
    }
    int cm = (lane >> 4) * 4, cn = lane & 15;
#pragma unroll
    for (int fm = 0; fm < 4; ++fm) {
#pragma unroll
        for (int fn = 0; fn < 4; ++fn) {
#pragma unroll
            for (int r = 0; r < 4; ++r) {
                int gm = m0 + wm + fm * 16 + cm + r;
                int gn = n0 + wn + fn * 16 + cn;
                if (gn < V_) {
                    int orow = (gm & 127) * S_ + (gm >> 7);
                    Cout[(size_t)orow * V_ + gn] = acc[fm][fn][r] + bias1[gn];
                }
            }
        }
    }
}

// ---------------- K1: per-step attention (R11/R15-proven) ----------------
__global__ __launch_bounds__(1024) void k_attn2(
    const __bf16* __restrict__ u_hs,      // [25088][512] bf16
    const unsigned* __restrict__ enc2,    // enc bf16 pairs [25088][256]
    const unsigned* __restrict__ W2,      // [512][256] packed Ww^T
    const float* __restrict__ Wb, const float* __restrict__ Aw,
    __bf16* __restrict__ Abuf,            // [128][1024]: read h (512..1023), write ctx (0..511)
    float* __restrict__ alphas, int s) {
    __shared__ __align__(16) float hs[512];
    __shared__ float wah[512];
    __shared__ float pc[2048];
    __shared__ float sc[200];             // holds E = exp(score)
    int b = blockIdx.x, t = threadIdx.x;
    int ln = t & 63, w = t >> 6;

    if (t < 256) {
        unsigned u = ((const unsigned*)Abuf)[b * 512 + 256 + t];
        hs[2 * t] = bflo(u); hs[2 * t + 1] = bfhi(u);
    }
    __syncthreads();
    {
        int jp = t & 255, kq = t >> 8;
        float a0 = 0.f, a1 = 0.f;
        const unsigned* wp = W2 + (size_t)(kq * 128) * 256 + jp;
        const float4* h4 = (const float4*)(hs + kq * 128);
#pragma unroll 4
        for (int k4 = 0; k4 < 32; ++k4) {
            float4 hk = h4[k4];
            unsigned w0 = wp[(k4 * 4 + 0) * 256];
            unsigned w1 = wp[(k4 * 4 + 1) * 256];
            unsigned w2 = wp[(k4 * 4 + 2) * 256];
            unsigned w3 = wp[(k4 * 4 + 3) * 256];
            a0 += hk.x * bflo(w0); a1 += hk.x * bfhi(w0);
            a0 += hk.y * bflo(w1); a1 += hk.y * bfhi(w1);
            a0 += hk.z * bflo(w2); a1 += hk.z * bfhi(w2);
            a0 += hk.w * bflo(w3); a1 += hk.w * bfhi(w3);
        }
        pc[kq * 512 + 2 * jp] = a0;
        pc[kq * 512 + 2 * jp + 1] = a1;
    }
    __syncthreads();
    if (t < 512)
        wah[t] = pc[t] + pc[512 + t] + pc[1024 + t] + pc[1536 + t] + Wb[t];
    __syncthreads();
    {
        float av[8], wv[8];
#pragma unroll
        for (int i = 0; i < 8; ++i) { av[i] = Aw[ln * 8 + i]; wv[i] = wah[ln * 8 + i]; }
        for (int n = w; n < NF_; n += 16) {
            bf16x8 u8 = *(const bf16x8*)(u_hs + ((size_t)(b * NF_ + n)) * 512 + ln * 8);
            float acc = 0.f;
#pragma unroll
            for (int i = 0; i < 8; ++i)
                acc += fast_tanhf((float)u8[i] + wv[i]) * av[i];
#pragma unroll
            for (int off = 32; off; off >>= 1) acc += __shfl_xor(acc, off);
            if (ln == 0) sc[n] = __expf(acc);
        }
    }
    __syncthreads();
    // wave-redundant normalizer: 196 = 3*64 + 4 (R11-fixed)
    float sum = sc[ln] + sc[ln + 64] + sc[ln + 128];
    if (ln < 4) sum += sc[ln + 192];
#pragma unroll
    for (int off = 32; off; off >>= 1) sum += __shfl_xor(sum, off);
    float inv = __fdividef(1.f, sum);
    if (t < NF_) alphas[((size_t)b * S_ + s) * NF_ + t] = sc[t] * inv;
    {
        int p2 = t & 255, q2 = t >> 8;
        float c0 = 0.f, c1 = 0.f;
        for (int i = q2; i < NF_; i += 4) {
            unsigned u = enc2[((size_t)(b * NF_ + i)) * 256 + p2];
            float a = sc[i];
            c0 += a * bflo(u); c1 += a * bfhi(u);
        }
        pc[q2 * 512 + 2 * p2] = c0;
        pc[q2 * 512 + 2 * p2 + 1] = c1;
    }
    __syncthreads();
    if (t < 512)
        Abuf[(size_t)b * 1024 + t] =
            (__bf16)((pc[t] + pc[512 + t] + pc[1024 + t] + pc[1536 + t]) * inv);
}

// ---------------- K2: gates MFMA GEMM, 256 blocks (R14/R15-proven) ----------------
__global__ __launch_bounds__(256) void k_gates(
    const __bf16* __restrict__ Abuf,      // [128][1024] = [ctx(s) | h(s)]
    const __bf16* __restrict__ Wcat,      // [2048][1024]
    const __bf16* __restrict__ gatespre,  // [3200][2048] bf16, gate-interleaved cols
    float* __restrict__ cbuf,             // [128][512] f32
    __bf16* __restrict__ AbufN,           // [128][1024]: write h(s+1) into cols 512..1023
    __bf16* __restrict__ Hall_bf,         // [26][128][512]
    int s) {
    __shared__ __align__(16) __bf16 As[2][16 * 64];   // 4 KB
    __shared__ __align__(16) __bf16 Bs[2][64 * 64];   // 16 KB
    __shared__ float Red[1024];                       // 4 KB
    __shared__ float Gs[16][68];                      // padded
    int t = threadIdx.x;
    int lane = t & 63, w = t >> 6;
    int m0 = blockIdx.x * 16, n0 = blockIdx.y * 64;
    int kh = w >> 1, nh = w & 1;
    f32x4 acc[2] = {};
    int ah = t >> 7;             // A-staging half
    int arow = (t & 127) >> 3;   // 0..15
    int ake = (t & 7) * 8;
    int akg = t & 7;
    int srow = t >> 3;           // 0..31 (B staging)
    int ke = (t & 7) * 8;
    int kgw = t & 7;

    for (int k0 = 0; k0 < 512; k0 += 64) {
        {   // A: 16 rows x 64 k x 2 halves (128 threads per half)
            int kb = ah * 512 + k0;
            bf16x8 av = *(const bf16x8*)(Abuf + (size_t)(m0 + arow) * 1024 + kb + ake);
            *(bf16x8*)&As[ah][arow * 64 + (akg ^ (arow & 7)) * 8] = av;
        }
#pragma unroll
        for (int h = 0; h < 2; ++h) {
            int kb = h * 512 + k0;
#pragma unroll
            for (int it = 0; it < 2; ++it) {
                int row = it * 32 + srow;
                bf16x8 bv = *(const bf16x8*)(Wcat + (size_t)(n0 + row) * 1024 + kb + ke);
                *(bf16x8*)&Bs[h][row * 64 + (kgw ^ (row & 7)) * 8] = bv;
            }
        }
        __syncthreads();
        bf16x8 af[2], bfr[2][2];
#pragma unroll
        for (int ks = 0; ks < 2; ++ks) {
            int ra = lane & 15;
            int kgl = ks * 4 + (lane >> 4);
            af[ks] = *(const bf16x8*)&As[kh][ra * 64 + ((kgl ^ (ra & 7))) * 8];
#pragma unroll
            for (int fn = 0; fn < 2; ++fn) {
                int rb = nh * 32 + fn * 16 + (lane & 15);
                bfr[fn][ks] = *(const bf16x8*)&Bs[kh][rb * 64 + ((kgl ^ (rb & 7))) * 8];
            }
        }
#pragma unroll
        for (int fn = 0; fn < 2; ++fn)
#pragma unroll
            for (int ks = 0; ks < 2; ++ks)
                acc[fn] = __builtin_amdgcn_mfma_f32_16x16x32_bf16(
                    af[ks], bfr[fn][ks], acc[fn], 0, 0, 0);
        __syncthreads();
    }
    int base = (nh * 64 + lane) * 8;
    if (kh == 1) {
#pragma unroll
        for (int fn = 0; fn < 2; ++fn)
#pragma unroll
            for (int r = 0; r < 4; ++r) Red[base + fn * 4 + r] = acc[fn][r];
    }
    __syncthreads();
    if (kh == 0) {
        int cm = (lane >> 4) * 4, cn = lane & 15;
#pragma unroll
        for (int fn = 0; fn < 2; ++fn)
#pragma unroll
            for (int r = 0; r < 4; ++r)
                Gs[cm + r][nh * 32 + fn * 16 + cn] = acc[fn][r] + Red[base + fn * 4 + r];
    }
    __syncthreads();
    {
        int row = t >> 4, jlo = t & 15;
        int b = m0 + row;
        int j = (n0 >> 6) * 16 + jlo;
        const __bf16* gp = gatespre + ((size_t)(s * B_ + b)) * G4_ + n0 + jlo;
        float qi = Gs[row][jlo]      + (float)gp[0];
        float qf = Gs[row][16 + jlo] + (float)gp[16];
        float qg = Gs[row][32 + jlo] + (float)gp[32];
        float qo = Gs[row][48 + jlo] + (float)gp[48];
        float ig = fast_sigf(qi), fg = fast_sigf(qf);
        float gg = fast_tanhf(qg), og = fast_sigf(qo);
        int ci = b * 512 + j;
        float cnew = fg * cbuf[ci] + ig * gg;
        float hn = og * fast_tanhf(cnew);
        cbuf[ci] = cnew;
        __bf16 hb = (__bf16)hn;
        AbufN[(size_t)b * 1024 + 512 + j] = hb;
        Hall_bf[(size_t)(s + 1) * 65536 + ci] = hb;
    }
}

extern "C" void kernel_launch(void* const* d_in, const int* in_sizes, int n_in,
                              void* d_out, int out_size, void* d_ws, size_t ws_size,
                              hipStream_t stream) {
    const int*   dec  = (const int*)d_in[0];
    const float* enc  = (const float*)d_in[1];
    const float* emb  = (const float*)d_in[2];
    const float* pose = (const float*)d_in[3];
    const float* Uw   = (const float*)d_in[4];
    const float* Ub   = (const float*)d_in[5];
    const float* Ww   = (const float*)d_in[6];
    const float* Wb   = (const float*)d_in[7];
    const float* Aw   = (const float*)d_in[8];
    // d_in[9] = Ab: cancels in softmax
    const float* ihw  = (const float*)d_in[10];
    const float* ihb  = (const float*)d_in[11];
    const float* icw  = (const float*)d_in[12];
    const float* icb  = (const float*)d_in[13];
    const float* W_ih = (const float*)d_in[14];
    const float* W_hh = (const float*)d_in[15];
    const float* b_ih = (const float*)d_in[16];
    const float* b_hh = (const float*)d_in[17];
    const float* fcw  = (const float*)d_in[18];
    const float* fcb  = (const float*)d_in[19];
    float* out = (float*)d_out;
    char*  wsb = (char*)d_ws;

    // ---- workspace layout (bytes), ~87 MB ----
    size_t o = 0;
    __bf16*   enc_bf   = (__bf16*)(wsb + o); o += (size_t)25088 * 512 * 2;
    __bf16*   u_hs_bf  = (__bf16*)(wsb + o); o += (size_t)25088 * 512 * 2;
    __bf16*   gpre_bf  = (__bf16*)(wsb + o); o += (size_t)3200 * 2048 * 2;
    __bf16*   Hall_bf  = (__bf16*)(wsb + o); o += (size_t)26 * 65536 * 2;
    float*    cbuf     = (float*)(wsb + o);  o += (size_t)65536 * 4;
    __bf16*   Abuf     = (__bf16*)(wsb + o); o += (size_t)2 * 128 * 1024 * 2;
    __bf16*   Uw_bf    = (__bf16*)(wsb + o); o += (size_t)262144 * 2;
    unsigned* W2       = (unsigned*)(wsb + o); o += (size_t)512 * 256 * 4;
    __bf16*   WihE_r   = (__bf16*)(wsb + o); o += (size_t)2048 * 256 * 2;
    __bf16*   embeds_bf= (__bf16*)(wsb + o); o += (size_t)3200 * 256 * 2;
    __bf16*   Wcat     = (__bf16*)(wsb + o); o += (size_t)2048 * 1024 * 2;
    float*    bsum_r   = (float*)(wsb + o);  o += (size_t)2048 * 4;
    __bf16*   fcw_bf   = (__bf16*)(wsb + o); o += (size_t)VPAD_ * 512 * 2;

    // ---- setup: one fused launch + init + one fused GEMM launch ----
    k_setup<<<25288, 256, 0, stream>>>(enc, enc_bf, Uw, Uw_bf, Ww, W2,
                                       W_ih, WihE_r, W_hh, Wcat,
                                       b_ih, b_hh, bsum_r,
                                       dec, emb, pose, embeds_bf, fcw, fcw_bf);
    k_init2<<<B_, 1024, 0, stream>>>(enc, ihw, ihb, icw, icb, Abuf, cbuf);
    k_gemms<<<1184, 256, 0, stream>>>(enc_bf, Uw_bf, Ub, u_hs_bf,
                                      embeds_bf, WihE_r, bsum_r, gpre_bf);

    // ---- 25 steps x 2 kernels (kernel boundary = the barrier) ----
    for (int s = 0; s < S_; ++s) {
        __bf16* Ap = Abuf + (size_t)(s & 1) * 131072;
        __bf16* An = Abuf + (size_t)((s + 1) & 1) * 131072;
        k_attn2<<<B_, 1024, 0, stream>>>(u_hs_bf, (const unsigned*)enc_bf, W2, Wb, Aw,
                                         Ap, out + 32000000, s);
        k_gates<<<dim3(8, 32), 256, 0, stream>>>(Ap, Wcat, gpre_bf, cbuf, An, Hall_bf, s);
    }

    // outs = Hall_bf[1..25] @ fcn_w^T + fcn_b -> f32 [B,S,V]  (XCD-swizzled, direct stores)
    k_fcn<<<dim3(25, 79), 256, 0, stream>>>(Hall_bf + 65536, fcw_bf, fcb, out);
}

// Round 19
// 1329.532 us; speedup vs baseline: 1.1778x; 1.0042x over previous
//
#include <hip/hip_runtime.h>

constexpr int B_ = 128, S_ = 25, NF_ = 196, ENC_ = 512, ATT_ = 512;
constexpr int H_ = 512, E_ = 256, V_ = 10000, G4_ = 2048;
constexpr int VPAD_ = 10112;  // 79*128

typedef __attribute__((ext_vector_type(8))) __bf16 bf16x8;
typedef __attribute__((ext_vector_type(4))) __bf16 bf16x4;
typedef __attribute__((ext_vector_type(4))) float f32x4;

__device__ __forceinline__ float bflo(unsigned u) {
    return __builtin_bit_cast(float, u << 16);
}
__device__ __forceinline__ float bfhi(unsigned u) {
    return __builtin_bit_cast(float, u & 0xffff0000u);
}
// clamp-free: e=inf/0 degrade gracefully to +-1 (no NaN possible for finite x)
__device__ __forceinline__ float fast_tanhf(float x) {
    float e = __expf(2.f * x);
    return 1.f - 2.f * __fdividef(1.f, e + 1.f);
}
__device__ __forceinline__ float fast_sigf(float x) {
    return __fdividef(1.f, 1.f + __expf(-x));
}

// gate-interleaved permutation: col n -> weight row pi(n)
__device__ __forceinline__ int gperm(int n) {
    int j = (n & 15) + ((n >> 6) << 4);
    int g = (n >> 4) & 3;
    return g * 512 + j;
}

// async global->LDS, 16B/lane. dest linear in lane order (rule #21); swizzle on global src.
__device__ __forceinline__ void gload16(const __bf16* src, __bf16* dst) {
    __builtin_amdgcn_global_load_lds(
        (const __attribute__((address_space(1))) unsigned*)src,
        (__attribute__((address_space(3))) unsigned*)dst, 16, 0, 0);
}

// ---------------- fused setup kernel (R13-proven) ----------------
__global__ __launch_bounds__(256) void k_setup(
    const float* __restrict__ enc, __bf16* __restrict__ enc_bf,
    const float* __restrict__ Uw, __bf16* __restrict__ Uw_bf,
    const float* __restrict__ Ww, unsigned* __restrict__ W2,
    const float* __restrict__ W_ih, __bf16* __restrict__ WihE_r,
    const float* __restrict__ W_hh, __bf16* __restrict__ Wcat,
    const float* __restrict__ b_ih, const float* __restrict__ b_hh,
    float* __restrict__ bsum_r,
    const int* __restrict__ dec, const float* __restrict__ emb,
    const float* __restrict__ pose, __bf16* __restrict__ embeds_bf,
    const float* __restrict__ fcw, __bf16* __restrict__ fcw_bf) {
    __shared__ float Ts[32][65];
    int bid = blockIdx.x, t = threadIdx.x;

    if (bid < 12544) {                       // enc cvt
        int i = bid * 256 + t;
        if (i < 3211264) {
            float4 v = *(const float4*)&enc[(size_t)i * 4];
            bf16x4 o;
            o[0] = (__bf16)v.x; o[1] = (__bf16)v.y; o[2] = (__bf16)v.z; o[3] = (__bf16)v.w;
            *(bf16x4*)&enc_bf[(size_t)i * 4] = o;
        }
    } else if (bid < 12800) {                // Uw cvt
        int i = (bid - 12544) * 256 + t;
        float4 v = *(const float4*)&Uw[(size_t)i * 4];
        bf16x4 o;
        o[0] = (__bf16)v.x; o[1] = (__bf16)v.y; o[2] = (__bf16)v.z; o[3] = (__bf16)v.w;
        *(bf16x4*)&Uw_bf[(size_t)i * 4] = o;
    } else if (bid < 12928) {                // pack_ww
        int l = bid - 12800;
        int k0 = (l & 15) * 32, j0 = (l >> 4) * 64;
        int c = t & 31, rr = t >> 5;
#pragma unroll
        for (int i = 0; i < 8; ++i) {
            int j = j0 + rr + i * 8;
            Ts[c][rr + i * 8] = Ww[(size_t)j * 512 + k0 + c];
        }
        __syncthreads();
#pragma unroll
        for (int i = 0; i < 4; ++i) {
            int kr = (t >> 5) + i * 8;
            int jc = t & 31;
            __bf16 b0 = (__bf16)Ts[kr][2 * jc], b1 = (__bf16)Ts[kr][2 * jc + 1];
            unsigned u = (unsigned)__builtin_bit_cast(unsigned short, b0)
                       | ((unsigned)__builtin_bit_cast(unsigned short, b1) << 16);
            W2[(size_t)(k0 + kr) * 256 + (j0 >> 1) + jc] = u;
        }
    } else if (bid < 14976) {                // cvt_wih_r
        int n = bid - 12928;
        int row = gperm(n);
        WihE_r[(size_t)n * 256 + t] = (__bf16)W_ih[(size_t)row * 768 + t];
    } else if (bid < 17024) {                // pack_wcat
        int n = bid - 14976;
        int row = gperm(n);
#pragma unroll
        for (int i = 0; i < 4; ++i) {
            int k = t + i * 256;
            float v = (k < 512) ? W_ih[(size_t)row * 768 + 256 + k]
                                : W_hh[(size_t)row * 512 + (k - 512)];
            Wcat[(size_t)n * 1024 + k] = (__bf16)v;
        }
    } else if (bid < 17032) {                // pack_biasr
        int n = (bid - 17024) * 256 + t;
        int row = gperm(n);
        bsum_r[n] = b_ih[row] + b_hh[row];
    } else if (bid < 20232) {                // embed
        int bx = bid - 17032;
        int s = bx >> 7, b = bx & 127;
        int tok = dec[b * S_ + s];
        embeds_bf[(size_t)bx * E_ + t] = (__bf16)(emb[tok * E_ + t] + pose[s * E_ + t]);
    } else {                                 // cvt_fcw (padded)
        int i = (bid - 20232) * 256 + t;
        if (i < VPAD_ * 512 / 4) {
            int e = i * 4;
            int row = e >> 9;
            bf16x4 o;
            if (row < V_) {
                float4 v = *(const float4*)&fcw[(size_t)row * 512 + (e & 511)];
                o[0] = (__bf16)v.x; o[1] = (__bf16)v.y; o[2] = (__bf16)v.z; o[3] = (__bf16)v.w;
            } else {
                o[0] = o[1] = o[2] = o[3] = (__bf16)0.f;
            }
            *(bf16x4*)&fcw_bf[(size_t)e] = o;
        }
    }
}

// mean_enc -> h0, c0 (R13-proven)
__global__ __launch_bounds__(1024) void k_init2(const float* __restrict__ enc,
                                                const float* __restrict__ ihw, const float* __restrict__ ihb,
                                                const float* __restrict__ icw, const float* __restrict__ icb,
                                                __bf16* __restrict__ Abuf0, float* __restrict__ cbuf) {
    __shared__ float pm[1024];
    __shared__ __align__(16) float mean[512];
    int b = blockIdx.x, t = threadIdx.x;
    int d = t & 511, q = t >> 9;
    const float* ep = enc + ((size_t)b * 196 + q * 98) * 512 + d;
    float sum = 0.f;
#pragma unroll 7
    for (int n = 0; n < 98; ++n) sum += ep[(size_t)n * 512];
    pm[t] = sum;
    __syncthreads();
    if (t < 512) mean[t] = (pm[t] + pm[t + 512]) * (1.f / 196.f);
    __syncthreads();
    int w = t >> 6, ln = t & 63;
    float4 m4a = *(const float4*)&mean[ln * 8];
    float4 m4b = *(const float4*)&mean[ln * 8 + 4];
#pragma unroll 4
    for (int i = 0; i < 32; ++i) {
        int j = i * 16 + w;
        const float4* wh = (const float4*)&ihw[(size_t)j * 512 + ln * 8];
        const float4* wc = (const float4*)&icw[(size_t)j * 512 + ln * 8];
        float4 ha = wh[0], hb = wh[1], ca = wc[0], cb = wc[1];
        float ah = m4a.x * ha.x + m4a.y * ha.y + m4a.z * ha.z + m4a.w * ha.w
                 + m4b.x * hb.x + m4b.y * hb.y + m4b.z * hb.z + m4b.w * hb.w;
        float ac = m4a.x * ca.x + m4a.y * ca.y + m4a.z * ca.z + m4a.w * ca.w
                 + m4b.x * cb.x + m4b.y * cb.y + m4b.z * cb.z + m4b.w * cb.w;
#pragma unroll
        for (int off = 32; off; off >>= 1) {
            ah += __shfl_xor(ah, off);
            ac += __shfl_xor(ac, off);
        }
        if (ln == 0) {
            Abuf0[(size_t)b * 1024 + 512 + j] = (__bf16)(ah + ihb[j]);
            cbuf[b * 512 + j] = ac + icb[j];
        }
    }
}

// ---------------- fused setup GEMMs, global_load_lds staging (R15) ----------------
__global__ __launch_bounds__(256) void k_gemms(
    const __bf16* __restrict__ Aa, const __bf16* __restrict__ Ba,
    const float* __restrict__ ba, __bf16* __restrict__ Ca,
    const __bf16* __restrict__ Ab, const __bf16* __restrict__ Bb,
    const float* __restrict__ bb, __bf16* __restrict__ Cb) {
    __shared__ __align__(16) __bf16 As[128 * 64];
    __shared__ __align__(16) __bf16 Bs[128 * 64];
    int bid = blockIdx.x, tid = threadIdx.x;
    const __bf16 *A, *Bm;
    const float* bias;
    __bf16* C;
    int lda, K, ldc, m0, n0;
    if (bid < 784) {
        A = Aa; Bm = Ba; bias = ba; C = Ca; lda = 512; K = 512; ldc = 512;
        m0 = (bid % 196) * 128; n0 = (bid / 196) * 128;
    } else {
        int i = bid - 784;
        A = Ab; Bm = Bb; bias = bb; C = Cb; lda = 256; K = 256; ldc = 2048;
        m0 = (i % 25) * 128; n0 = (i / 25) * 128;
    }
    int lane = tid & 63, w = tid >> 6;
    int wm = (w & 1) * 64, wn = (w >> 1) * 64;
    f32x4 acc[4][4] = {};
    int lrow = lane >> 3;
    int kgd = lane & 7;

    for (int k0 = 0; k0 < K; k0 += 64) {
#pragma unroll
        for (int i = 0; i < 4; ++i) {
            int row = w * 32 + i * 8 + lrow;
            int kgs = kgd ^ (row & 7);
            gload16(A + (size_t)(m0 + row) * lda + k0 + kgs * 8, &As[row * 64 + kgd * 8]);
            gload16(Bm + (size_t)(n0 + row) * K + k0 + kgs * 8, &Bs[row * 64 + kgd * 8]);
        }
        __syncthreads();
        bf16x8 af[4][2], bfr[4][2];
#pragma unroll
        for (int f = 0; f < 4; ++f) {
#pragma unroll
            for (int ks = 0; ks < 2; ++ks) {
                int ra = wm + f * 16 + (lane & 15);
                int rb = wn + f * 16 + (lane & 15);
                int kgl = ks * 4 + (lane >> 4);
                af[f][ks]  = *(const bf16x8*)&As[ra * 64 + (kgl ^ (ra & 7)) * 8];
                bfr[f][ks] = *(const bf16x8*)&Bs[rb * 64 + (kgl ^ (rb & 7)) * 8];
            }
        }
#pragma unroll
        for (int fm = 0; fm < 4; ++fm)
#pragma unroll
            for (int fn = 0; fn < 4; ++fn)
#pragma unroll
                for (int ks = 0; ks < 2; ++ks)
                    acc[fm][fn] = __builtin_amdgcn_mfma_f32_16x16x32_bf16(
                        af[fm][ks], bfr[fn][ks], acc[fm][fn], 0, 0, 0);
        __syncthreads();
    }
    int cm = (lane >> 4) * 4, cn = lane & 15;
#pragma unroll
    for (int fm = 0; fm < 4; ++fm)
#pragma unroll
        for (int fn = 0; fn < 4; ++fn)
#pragma unroll
            for (int r = 0; r < 4; ++r) {
                int gm = m0 + wm + fm * 16 + cm + r;
                int gn = n0 + wn + fn * 16 + cn;
                C[(size_t)gm * ldc + gn] = (__bf16)(acc[fm][fn][r] + bias[gn]);
            }
}

// ---------------- fcn GEMM (R15) ----------------
__global__ __launch_bounds__(256) void k_fcn(
    const __bf16* __restrict__ A, const __bf16* __restrict__ Bm,
    const float* __restrict__ bias1, float* __restrict__ Cout) {
    __shared__ __align__(16) __bf16 As[128 * 64];
    __shared__ __align__(16) __bf16 Bs[128 * 64];
    int tid = threadIdx.x;
    int lane = tid & 63, w = tid >> 6;
    int nwg = gridDim.x * gridDim.y;
    int bid = blockIdx.y * gridDim.x + blockIdx.x;
    int q = nwg >> 3, r0 = nwg & 7;
    int xcd = bid & 7, lid = bid >> 3;
    int wgid = (xcd < r0) ? xcd * (q + 1) + lid : r0 * (q + 1) + (xcd - r0) * q + lid;
    int m0 = (wgid % gridDim.x) * 128;
    int n0 = (wgid / gridDim.x) * 128;

    int wm = (w & 1) * 64, wn = (w >> 1) * 64;
    f32x4 acc[4][4] = {};
    int lrow = lane >> 3;
    int kgd = lane & 7;

    for (int k0 = 0; k0 < 512; k0 += 64) {
#pragma unroll
        for (int i = 0; i < 4; ++i) {
            int row = w * 32 + i * 8 + lrow;
            int kgs = kgd ^ (row & 7);
            gload16(A + (size_t)(m0 + row) * 512 + k0 + kgs * 8, &As[row * 64 + kgd * 8]);
            gload16(Bm + (size_t)(n0 + row) * 512 + k0 + kgs * 8, &Bs[row * 64 + kgd * 8]);
        }
        __syncthreads();
        bf16x8 af[4][2], bfr[4][2];
#pragma unroll
        for (int f = 0; f < 4; ++f) {
#pragma unroll
            for (int ks = 0; ks < 2; ++ks) {
                int ra = wm + f * 16 + (lane & 15);
                int rb = wn + f * 16 + (lane & 15);
                int kgl = ks * 4 + (lane >> 4);
                af[f][ks]  = *(const bf16x8*)&As[ra * 64 + (kgl ^ (ra & 7)) * 8];
                bfr[f][ks] = *(const bf16x8*)&Bs[rb * 64 + (kgl ^ (rb & 7)) * 8];
            }
        }
#pragma unroll
        for (int fm = 0; fm < 4; ++fm)
#pragma unroll
            for (int fn = 0; fn < 4; ++fn)
#pragma unroll
                for (int ks = 0; ks < 2; ++ks)
                    acc[fm][fn] = __builtin_amdgcn_mfma_f32_16x16x32_bf16(
                        af[fm][ks], bfr[fn][ks], acc[fm][fn], 0, 0, 0);
        __syncthreads();
    }
    int cm = (lane >> 4) * 4, cn = lane & 15;
#pragma unroll
    for (int fm = 0; fm < 4; ++fm) {
#pragma unroll
        for (int fn = 0; fn < 4; ++fn) {
#pragma unroll
            for (int r = 0; r < 4; ++r) {
                int gm = m0 + wm + fm * 16 + cm + r;
                int gn = n0 + wn + fn * 16 + cn;
                if (gn < V_) {
                    int orow = (gm & 127) * S_ + (gm >> 7);
                    Cout[(size_t)orow * V_ + gn] = acc[fm][fn][r] + bias1[gn];
                }
            }
        }
    }
}

// ---------------- K1: per-step attention (R11/R15-proven) ----------------
__global__ __launch_bounds__(1024) void k_attn2(
    const __bf16* __restrict__ u_hs,      // [25088][512] bf16
    const unsigned* __restrict__ enc2,    // enc bf16 pairs [25088][256]
    const unsigned* __restrict__ W2,      // [512][256] packed Ww^T
    const float* __restrict__ Wb, const float* __restrict__ Aw,
    __bf16* __restrict__ Abuf,            // [128][1024]: read h (512..1023), write ctx (0..511)
    float* __restrict__ alphas, int s) {
    __shared__ __align__(16) float hs[512];
    __shared__ float wah[512];
    __shared__ float pc[2048];
    __shared__ float sc[200];             // holds E = exp(score)
    int b = blockIdx.x, t = threadIdx.x;
    int ln = t & 63, w = t >> 6;

    if (t < 256) {
        unsigned u = ((const unsigned*)Abuf)[b * 512 + 256 + t];
        hs[2 * t] = bflo(u); hs[2 * t + 1] = bfhi(u);
    }
    __syncthreads();
    {
        int jp = t & 255, kq = t >> 8;
        float a0 = 0.f, a1 = 0.f;
        const unsigned* wp = W2 + (size_t)(kq * 128) * 256 + jp;
        const float4* h4 = (const float4*)(hs + kq * 128);
#pragma unroll 4
        for (int k4 = 0; k4 < 32; ++k4) {
            float4 hk = h4[k4];
            unsigned w0 = wp[(k4 * 4 + 0) * 256];
            unsigned w1 = wp[(k4 * 4 + 1) * 256];
            unsigned w2 = wp[(k4 * 4 + 2) * 256];
            unsigned w3 = wp[(k4 * 4 + 3) * 256];
            a0 += hk.x * bflo(w0); a1 += hk.x * bfhi(w0);
            a0 += hk.y * bflo(w1); a1 += hk.y * bfhi(w1);
            a0 += hk.z * bflo(w2); a1 += hk.z * bfhi(w2);
            a0 += hk.w * bflo(w3); a1 += hk.w * bfhi(w3);
        }
        pc[kq * 512 + 2 * jp] = a0;
        pc[kq * 512 + 2 * jp + 1] = a1;
    }
    __syncthreads();
    if (t < 512)
        wah[t] = pc[t] + pc[512 + t] + pc[1024 + t] + pc[1536 + t] + Wb[t];
    __syncthreads();
    {
        float av[8], wv[8];
#pragma unroll
        for (int i = 0; i < 8; ++i) { av[i] = Aw[ln * 8 + i]; wv[i] = wah[ln * 8 + i]; }
        for (int n = w; n < NF_; n += 16) {
            bf16x8 u8 = *(const bf16x8*)(u_hs + ((size_t)(b * NF_ + n)) * 512 + ln * 8);
            float acc = 0.f;
#pragma unroll
            for (int i = 0; i < 8; ++i)
                acc += fast_tanhf((float)u8[i] + wv[i]) * av[i];
#pragma unroll
            for (int off = 32; off; off >>= 1) acc += __shfl_xor(acc, off);
            if (ln == 0) sc[n] = __expf(acc);
        }
    }
    __syncthreads();
    // wave-redundant normalizer: 196 = 3*64 + 4 (R11-fixed)
    float sum = sc[ln] + sc[ln + 64] + sc[ln + 128];
    if (ln < 4) sum += sc[ln + 192];
#pragma unroll
    for (int off = 32; off; off >>= 1) sum += __shfl_xor(sum, off);
    float inv = __fdividef(1.f, sum);
    if (t < NF_) alphas[((size_t)b * S_ + s) * NF_ + t] = sc[t] * inv;
    {
        int p2 = t & 255, q2 = t >> 8;
        float c0 = 0.f, c1 = 0.f;
        for (int i = q2; i < NF_; i += 4) {
            unsigned u = enc2[((size_t)(b * NF_ + i)) * 256 + p2];
            float a = sc[i];
            c0 += a * bflo(u); c1 += a * bfhi(u);
        }
        pc[q2 * 512 + 2 * p2] = c0;
        pc[q2 * 512 + 2 * p2 + 1] = c1;
    }
    __syncthreads();
    if (t < 512)
        Abuf[(size_t)b * 1024 + t] =
            (__bf16)((pc[t] + pc[512 + t] + pc[1024 + t] + pc[1536 + t]) * inv);
}

// ---------------- K2: gates MFMA GEMM, 256 blocks (R14/R15-proven) ----------------
__global__ __launch_bounds__(256) void k_gates(
    const __bf16* __restrict__ Abuf,      // [128][1024] = [ctx(s) | h(s)]
    const __bf16* __restrict__ Wcat,      // [2048][1024]
    const __bf16* __restrict__ gatespre,  // [3200][2048] bf16, gate-interleaved cols
    float* __restrict__ cbuf,             // [128][512] f32
    __bf16* __restrict__ AbufN,           // [128][1024]: write h(s+1) into cols 512..1023
    __bf16* __restrict__ Hall_bf,         // [26][128][512]
    int s) {
    __shared__ __align__(16) __bf16 As[2][16 * 64];   // 4 KB
    __shared__ __align__(16) __bf16 Bs[2][64 * 64];   // 16 KB
    __shared__ float Red[1024];                       // 4 KB
    __shared__ float Gs[16][68];                      // padded
    int t = threadIdx.x;
    int lane = t & 63, w = t >> 6;
    int m0 = blockIdx.x * 16, n0 = blockIdx.y * 64;
    int kh = w >> 1, nh = w & 1;
    f32x4 acc[2] = {};
    int ah = t >> 7;             // A-staging half
    int arow = (t & 127) >> 3;   // 0..15
    int ake = (t & 7) * 8;
    int akg = t & 7;
    int srow = t >> 3;           // 0..31 (B staging)
    int ke = (t & 7) * 8;
    int kgw = t & 7;

    for (int k0 = 0; k0 < 512; k0 += 64) {
        {   // A: 16 rows x 64 k x 2 halves (128 threads per half)
            int kb = ah * 512 + k0;
            bf16x8 av = *(const bf16x8*)(Abuf + (size_t)(m0 + arow) * 1024 + kb + ake);
            *(bf16x8*)&As[ah][arow * 64 + (akg ^ (arow & 7)) * 8] = av;
        }
#pragma unroll
        for (int h = 0; h < 2; ++h) {
            int kb = h * 512 + k0;
#pragma unroll
            for (int it = 0; it < 2; ++it) {
                int row = it * 32 + srow;
                bf16x8 bv = *(const bf16x8*)(Wcat + (size_t)(n0 + row) * 1024 + kb + ke);
                *(bf16x8*)&Bs[h][row * 64 + (kgw ^ (row & 7)) * 8] = bv;
            }
        }
        __syncthreads();
        bf16x8 af[2], bfr[2][2];
#pragma unroll
        for (int ks = 0; ks < 2; ++ks) {
            int ra = lane & 15;
            int kgl = ks * 4 + (lane >> 4);
            af[ks] = *(const bf16x8*)&As[kh][ra * 64 + ((kgl ^ (ra & 7))) * 8];
#pragma unroll
            for (int fn = 0; fn < 2; ++fn) {
                int rb = nh * 32 + fn * 16 + (lane & 15);
                bfr[fn][ks] = *(const bf16x8*)&Bs[kh][rb * 64 + ((kgl ^ (rb & 7))) * 8];
            }
        }
#pragma unroll
        for (int fn = 0; fn < 2; ++fn)
#pragma unroll
            for (int ks = 0; ks < 2; ++ks)
                acc[fn] = __builtin_amdgcn_mfma_f32_16x16x32_bf16(
                    af[ks], bfr[fn][ks], acc[fn], 0, 0, 0);
        __syncthreads();
    }
    int base = (nh * 64 + lane) * 8;
    if (kh == 1) {
#pragma unroll
        for (int fn = 0; fn < 2; ++fn)
#pragma unroll
            for (int r = 0; r < 4; ++r) Red[base + fn * 4 + r] = acc[fn][r];
    }
    __syncthreads();
    if (kh == 0) {
        int cm = (lane >> 4) * 4, cn = lane & 15;
#pragma unroll
        for (int fn = 0; fn < 2; ++fn)
#pragma unroll
            for (int r = 0; r < 4; ++r)
                Gs[cm + r][nh * 32 + fn * 16 + cn] = acc[fn][r] + Red[base + fn * 4 + r];
    }
    __syncthreads();
    {
        int row = t >> 4, jlo = t & 15;
        int b = m0 + row;
        int j = (n0 >> 6) * 16 + jlo;
        const __bf16* gp = gatespre + ((size_t)(s * B_ + b)) * G4_ + n0 + jlo;
        float qi = Gs[row][jlo]      + (float)gp[0];
        float qf = Gs[row][16 + jlo] + (float)gp[16];
        float qg = Gs[row][32 + jlo] + (float)gp[32];
        float qo = Gs[row][48 + jlo] + (float)gp[48];
        float ig = fast_sigf(qi), fg = fast_sigf(qf);
        float gg = fast_tanhf(qg), og = fast_sigf(qo);
        int ci = b * 512 + j;
        float cnew = fg * cbuf[ci] + ig * gg;
        float hn = og * fast_tanhf(cnew);
        cbuf[ci] = cnew;
        __bf16 hb = (__bf16)hn;
        AbufN[(size_t)b * 1024 + 512 + j] = hb;
        Hall_bf[(size_t)(s + 1) * 65536 + ci] = hb;
    }
}

extern "C" void kernel_launch(void* const* d_in, const int* in_sizes, int n_in,
                              void* d_out, int out_size, void* d_ws, size_t ws_size,
                              hipStream_t stream) {
    const int*   dec  = (const int*)d_in[0];
    const float* enc  = (const float*)d_in[1];
    const float* emb  = (const float*)d_in[2];
    const float* pose = (const float*)d_in[3];
    const float* Uw   = (const float*)d_in[4];
    const float* Ub   = (const float*)d_in[5];
    const float* Ww   = (const float*)d_in[6];
    const float* Wb   = (const float*)d_in[7];
    const float* Aw   = (const float*)d_in[8];
    // d_in[9] = Ab: cancels in softmax
    const float* ihw  = (const float*)d_in[10];
    const float* ihb  = (const float*)d_in[11];
    const float* icw  = (const float*)d_in[12];
    const float* icb  = (const float*)d_in[13];
    const float* W_ih = (const float*)d_in[14];
    const float* W_hh = (const float*)d_in[15];
    const float* b_ih = (const float*)d_in[16];
    const float* b_hh = (const float*)d_in[17];
    const float* fcw  = (const float*)d_in[18];
    const float* fcb  = (const float*)d_in[19];
    float* out = (float*)d_out;
    char*  wsb = (char*)d_ws;

    // ---- workspace layout (bytes), ~87 MB ----
    size_t o = 0;
    __bf16*   enc_bf   = (__bf16*)(wsb + o); o += (size_t)25088 * 512 * 2;
    __bf16*   u_hs_bf  = (__bf16*)(wsb + o); o += (size_t)25088 * 512 * 2;
    __bf16*   gpre_bf  = (__bf16*)(wsb + o); o += (size_t)3200 * 2048 * 2;
    __bf16*   Hall_bf  = (__bf16*)(wsb + o); o += (size_t)26 * 65536 * 2;
    float*    cbuf     = (float*)(wsb + o);  o += (size_t)65536 * 4;
    __bf16*   Abuf     = (__bf16*)(wsb + o); o += (size_t)2 * 128 * 1024 * 2;
    __bf16*   Uw_bf    = (__bf16*)(wsb + o); o += (size_t)262144 * 2;
    unsigned* W2       = (unsigned*)(wsb + o); o += (size_t)512 * 256 * 4;
    __bf16*   WihE_r   = (__bf16*)(wsb + o); o += (size_t)2048 * 256 * 2;
    __bf16*   embeds_bf= (__bf16*)(wsb + o); o += (size_t)3200 * 256 * 2;
    __bf16*   Wcat     = (__bf16*)(wsb + o); o += (size_t)2048 * 1024 * 2;
    float*    bsum_r   = (float*)(wsb + o);  o += (size_t)2048 * 4;
    __bf16*   fcw_bf   = (__bf16*)(wsb + o); o += (size_t)VPAD_ * 512 * 2;

    // ---- setup: one fused launch + init + one fused GEMM launch ----
    k_setup<<<25288, 256, 0, stream>>>(enc, enc_bf, Uw, Uw_bf, Ww, W2,
                                       W_ih, WihE_r, W_hh, Wcat,
                                       b_ih, b_hh, bsum_r,
                                       dec, emb, pose, embeds_bf, fcw, fcw_bf);
    k_init2<<<B_, 1024, 0, stream>>>(enc, ihw, ihb, icw, icb, Abuf, cbuf);
    k_gemms<<<1184, 256, 0, stream>>>(enc_bf, Uw_bf, Ub, u_hs_bf,
                                      embeds_bf, WihE_r, bsum_r, gpre_bf);

    // ---- 25 steps x 2 kernels (kernel boundary = the barrier) ----
    for (int s = 0; s < S_; ++s) {
        __bf16* Ap = Abuf + (size_t)(s & 1) * 131072;
        __bf16* An = Abuf + (size_t)((s + 1) & 1) * 131072;
        k_attn2<<<B_, 1024, 0, stream>>>(u_hs_bf, (const unsigned*)enc_bf, W2, Wb, Aw,
                                         Ap, out + 32000000, s);
        k_gates<<<dim3(8, 32), 256, 0, stream>>>(Ap, Wcat, gpre_bf, cbuf, An, Hall_bf, s);
    }

    // outs = Hall_bf[1..25] @ fcn_w^T + fcn_b -> f32 [B,S,V]  (XCD-swizzled, direct stores)
    k_fcn<<<dim3(25, 79), 256, 0, stream>>>(Hall_bf + 65536, fcw_bf, fcb, out);
}